// Round 1
// baseline (1271.570 us; speedup 1.0000x reference)
//
#include <hip/hip_runtime.h>
#include <hip/hip_bf16.h>

#define N_ATOMS 400000
#define MAX_D   4
#define NDEG_   5
#define B_GR    16384
#define NTASK   12

__device__ __forceinline__ float selu_f(float x) {
    const float a = 1.6732632423543772f, s = 1.0507009873554805f;
    return x > 0.f ? s * x : s * a * (__expf(x) - 1.f);
}

// ---------------- Graph conv layer ----------------
// One block: stages Ws/Wn/b in LDS once, then grid-strides over atom tiles.
// Phase A: load self row + masked neighbor-sum into LDS.
// Phase B: thread = (local atom, out feature): 2 matvecs + bias, selu.
template<int FI, int FO, int TA>
__launch_bounds__(256)
__global__ void conv_kernel(const float* __restrict__ x,
                            const float* __restrict__ Ws,
                            const float* __restrict__ Wn,
                            const float* __restrict__ bias,
                            const int*   __restrict__ nbr,
                            const int*   __restrict__ deg,
                            float*       __restrict__ out)
{
    __shared__ float ws_lds[NDEG_ * FI * FO];
    __shared__ float wn_lds[NDEG_ * FI * FO];
    __shared__ float b_lds[NDEG_ * FO];
    __shared__ float xs[TA * FI];
    __shared__ float ns[TA * FI];
    __shared__ int   dl[TA];

    for (int e = threadIdx.x; e < NDEG_ * FI * FO; e += 256) {
        ws_lds[e] = Ws[e];
        wn_lds[e] = Wn[e];
    }
    for (int e = threadIdx.x; e < NDEG_ * FO; e += 256) b_lds[e] = bias[e];

    const int ntiles = (N_ATOMS + TA - 1) / TA;
    for (int tile = blockIdx.x; tile < ntiles; tile += gridDim.x) {
        const int a0  = tile * TA;
        const int cnt = min(TA, N_ATOMS - a0);
        __syncthreads();   // previous tile phase B done (and weights staged on iter 0 path via next sync)
        if (threadIdx.x < cnt) dl[threadIdx.x] = deg[a0 + threadIdx.x];
        for (int e = threadIdx.x; e < cnt * FI; e += 256) {
            const int al = e / FI, f = e - al * FI;
            const int atom = a0 + al;
            xs[e] = x[atom * FI + f];
            const int d = deg[atom];
            const int* nb = nbr + atom * MAX_D;
            float sacc = 0.f;
            #pragma unroll
            for (int j = 0; j < MAX_D; ++j) {
                if (j < d) sacc += x[nb[j] * FI + f];
            }
            ns[e] = sacc;
        }
        __syncthreads();   // xs/ns ready; weights staged (first iteration)
        for (int e = threadIdx.x; e < cnt * FO; e += 256) {
            const int al = e / FO, o = e - al * FO;
            const int d = dl[al];
            float acc = b_lds[d * FO + o];
            const float* wsp = ws_lds + d * FI * FO + o;
            const float* wnp = wn_lds + d * FI * FO + o;
            const float* xp  = xs + al * FI;
            const float* np  = ns + al * FI;
            #pragma unroll 5
            for (int f = 0; f < FI; ++f) {
                acc += xp[f] * wsp[f * FO] + np[f] * wnp[f * FO];
            }
            out[(a0 + al) * FO + o] = selu_f(acc);
        }
    }
}

// ---------------- GraphGather readout + dense->softmax head ----------------
// One wave per graph. Binary-search segment bounds in sorted membership.
__launch_bounds__(64)
__global__ void readout_kernel(const float* __restrict__ x4,
                               const int*   __restrict__ mem,
                               const float* __restrict__ Wd2,
                               const float* __restrict__ bd2,
                               float*       __restrict__ p)
{
    const int g = blockIdx.x;
    const int t = threadIdx.x;

    int lo = 0, hi = N_ATOMS;                    // lower_bound(g)
    while (lo < hi) { int mid = (lo + hi) >> 1; if (mem[mid] < g) lo = mid + 1; else hi = mid; }
    int lo2 = lo, hi2 = N_ATOMS;                 // lower_bound(g+1)
    while (lo2 < hi2) { int mid = (lo2 + hi2) >> 1; if (mem[mid] < g + 1) lo2 = mid + 1; else hi2 = mid; }

    __shared__ float r[72];
    if (t < 36) {
        float s = 0.f, m = -3.4e38f;
        for (int a = lo; a < lo2; ++a) {
            float v = x4[a * 36 + t];
            s += v;
            m = fmaxf(m, v);
        }
        if (lo2 == lo) m = 0.f;                  // empty graph -> 0
        r[t]      = selu_f(s);
        r[36 + t] = selu_f(m);
    }
    __syncthreads();
    if (t < 24) {
        float acc = bd2[t];
        #pragma unroll
        for (int f = 0; f < 72; ++f) acc += r[f] * Wd2[f * 24 + t];
        // pairwise softmax: partner lane is t^1
        float part = __shfl_xor(acc, 1);
        p[g * 24 + t] = 1.f / (1.f + __expf(part - acc));
    }
}

// ---------------- Head: y1 = p @ Wl1 + bl1 ----------------
__launch_bounds__(256)
__global__ void dense1_kernel(const float* __restrict__ p,
                              const float* __restrict__ Wl1,
                              const float* __restrict__ bl1,
                              float*       __restrict__ y1)
{
    const int idx = blockIdx.x * 256 + threadIdx.x;
    if (idx >= B_GR * 96) return;
    const int row = idx / 96, c = idx - row * 96;
    float acc = bl1[c];
    const float* pr = p + row * 24;
    #pragma unroll
    for (int f = 0; f < 24; ++f) acc += pr[f] * Wl1[f * 96 + c];
    y1[idx] = acc;
}

// ---------------- Column mean/rstd over batch (deterministic tree) ----------------
template<int C>
__launch_bounds__(256)
__global__ void stats_kernel(const float* __restrict__ y, float* __restrict__ st)
{
    const int c = blockIdx.x;
    float s = 0.f, q = 0.f;
    for (int r = threadIdx.x; r < B_GR; r += 256) {
        const float v = y[r * C + c];
        s += v; q += v * v;
    }
    __shared__ float ss[256], qq[256];
    ss[threadIdx.x] = s; qq[threadIdx.x] = q;
    __syncthreads();
    for (int off = 128; off > 0; off >>= 1) {
        if (threadIdx.x < off) {
            ss[threadIdx.x] += ss[threadIdx.x + off];
            qq[threadIdx.x] += qq[threadIdx.x + off];
        }
        __syncthreads();
    }
    if (threadIdx.x == 0) {
        const float mean = ss[0] / (float)B_GR;
        const float var  = qq[0] / (float)B_GR - mean * mean;
        st[c]     = mean;
        st[C + c] = rsqrtf(var + 1e-5f);
    }
}

// ---------------- h1 = relu(bn(y1)); y2 = h1 @ Wl2 + bl2 ----------------
__launch_bounds__(256)
__global__ void dense2_kernel(const float* __restrict__ y1,
                              const float* __restrict__ st1,
                              const float* __restrict__ g1,
                              const float* __restrict__ be1,
                              const float* __restrict__ Wl2,
                              const float* __restrict__ bl2,
                              float*       __restrict__ y2)
{
    __shared__ float h[4 * 96];
    const int r0 = blockIdx.x * 4;
    for (int e = threadIdx.x; e < 4 * 96; e += 256) {
        const int rr = e / 96, c = e - rr * 96;
        float v = y1[(r0 + rr) * 96 + c];
        v = (v - st1[c]) * st1[96 + c] * g1[c] + be1[c];
        h[e] = fmaxf(v, 0.f);
    }
    __syncthreads();
    for (int e = threadIdx.x; e < 4 * 63; e += 256) {
        const int rr = e / 63, o = e - rr * 63;
        float acc = bl2[o];
        #pragma unroll
        for (int f = 0; f < 96; ++f) acc += h[rr * 96 + f] * Wl2[f * 63 + o];
        y2[(r0 + rr) * 63 + o] = acc;
    }
}

// ---------------- h2 = relu(bn(y2)); out = sigmoid(h2 @ Wl3 + bl3) ----------------
__launch_bounds__(320)
__global__ void dense3_kernel(const float* __restrict__ y2,
                              const float* __restrict__ st2,
                              const float* __restrict__ g2,
                              const float* __restrict__ be2,
                              const float* __restrict__ Wl3,
                              const float* __restrict__ bl3,
                              float*       __restrict__ out)
{
    __shared__ float h[2 * 63];
    const int r0 = blockIdx.x * 2;
    for (int e = threadIdx.x; e < 2 * 63; e += 320) {
        const int rr = e / 63, c = e - rr * 63;
        float v = y2[(r0 + rr) * 63 + c];
        v = (v - st2[c]) * st2[63 + c] * g2[c] + be2[c];
        h[e] = fmaxf(v, 0.f);
    }
    __syncthreads();
    for (int e = threadIdx.x; e < 2 * 138; e += 320) {
        const int rr = e / 138, o = e - rr * 138;
        float acc = bl3[o];
        #pragma unroll
        for (int f = 0; f < 63; ++f) acc += h[rr * 63 + f] * Wl3[f * 138 + o];
        out[(r0 + rr) * 138 + o] = 1.f / (1.f + __expf(-acc));
    }
}

extern "C" void kernel_launch(void* const* d_in, const int* in_sizes, int n_in,
                              void* d_out, int out_size, void* d_ws, size_t ws_size,
                              hipStream_t stream)
{
    (void)in_sizes; (void)n_in; (void)out_size; (void)ws_size;

    const float* af  = (const float*)d_in[0];
    const float* Ws1 = (const float*)d_in[1];
    const float* Wn1 = (const float*)d_in[2];
    const float* b1  = (const float*)d_in[3];
    const float* Ws2 = (const float*)d_in[4];
    const float* Wn2 = (const float*)d_in[5];
    const float* b2  = (const float*)d_in[6];
    const float* Ws3 = (const float*)d_in[7];
    const float* Wn3 = (const float*)d_in[8];
    const float* b3  = (const float*)d_in[9];
    const float* Ws4 = (const float*)d_in[10];
    const float* Wn4 = (const float*)d_in[11];
    const float* b4  = (const float*)d_in[12];
    const float* Wd2 = (const float*)d_in[13];
    const float* bd2 = (const float*)d_in[14];
    const float* Wl1 = (const float*)d_in[15];
    const float* bl1 = (const float*)d_in[16];
    const float* g1  = (const float*)d_in[17];
    const float* be1 = (const float*)d_in[18];
    const float* Wl2 = (const float*)d_in[19];
    const float* bl2 = (const float*)d_in[20];
    const float* g2  = (const float*)d_in[21];
    const float* be2 = (const float*)d_in[22];
    const float* Wl3 = (const float*)d_in[23];
    const float* bl3 = (const float*)d_in[24];
    const int*   nbr = (const int*)d_in[25];
    const int*   deg = (const int*)d_in[26];
    const int*   mem = (const int*)d_in[27];

    float* ws = (float*)d_ws;
    // bufA: x1 (N*15) then x3 (N*27); later head scratch. bufB: x2 (N*20) then x4 (N*36).
    float* bufA = ws;
    float* bufB = ws + (size_t)N_ATOMS * 27;
    float* x1 = bufA;
    float* x2 = bufB;
    float* x3 = bufA;
    float* x4 = bufB;
    float* p   = bufA;                       // B*24  (x3 dead after conv4)
    float* y1  = bufA + 393216;              // B*96
    float* y2  = bufA + 393216 + 1572864;    // B*63
    float* st1 = bufA + 393216 + 1572864 + 1032192;        // 192
    float* st2 = st1 + 192;                                 // 126

    conv_kernel<75, 15, 17><<<2048, 256, 0, stream>>>(af, Ws1, Wn1, b1, nbr, deg, x1);
    conv_kernel<15, 20, 12><<<2048, 256, 0, stream>>>(x1, Ws2, Wn2, b2, nbr, deg, x2);
    conv_kernel<20, 27,  9><<<2048, 256, 0, stream>>>(x2, Ws3, Wn3, b3, nbr, deg, x3);
    conv_kernel<27, 36,  7><<<2048, 256, 0, stream>>>(x3, Ws4, Wn4, b4, nbr, deg, x4);

    readout_kernel<<<B_GR, 64, 0, stream>>>(x4, mem, Wd2, bd2, p);

    dense1_kernel<<<(B_GR * 96) / 256, 256, 0, stream>>>(p, Wl1, bl1, y1);
    stats_kernel<96><<<96, 256, 0, stream>>>(y1, st1);
    dense2_kernel<<<B_GR / 4, 256, 0, stream>>>(y1, st1, g1, be1, Wl2, bl2, y2);
    stats_kernel<63><<<63, 256, 0, stream>>>(y2, st2);
    dense3_kernel<<<B_GR / 2, 320, 0, stream>>>(y2, st2, g2, be2, Wl3, bl3, (float*)d_out);
}

// Round 2
// 1028.310 us; speedup vs baseline: 1.2366x; 1.2366x over previous
//
#include <hip/hip_runtime.h>
#include <hip/hip_bf16.h>

#define N_ATOMS 400000
#define MAX_D   4
#define NDEG_   5
#define B_GR    16384
#define NTASK   12
#define NSUM_CAP 7500000   // floats of nsum scratch (30 MB)

__device__ __forceinline__ float selu_f(float x) {
    const float a = 1.6732632423543772f, s = 1.0507009873554805f;
    return x > 0.f ? s * x : s * a * (__expf(x) - 1.f);
}

// ---------------- Gather: masked neighbor feature sum ----------------
// nsum[al][f] = sum_{j<deg[a0+al]} x[nbr[a0+al][j]][f]
// No LDS, no barriers -> max occupancy, 4 loads in flight per lane.
template<int FI>
__launch_bounds__(256)
__global__ void gather_kernel(const float* __restrict__ x,
                              const int*   __restrict__ nbr,
                              const int*   __restrict__ deg,
                              float*       __restrict__ nsum,
                              int a0, int total /* = cnt*FI */)
{
    for (int e = blockIdx.x * 256 + threadIdx.x; e < total; e += gridDim.x * 256) {
        const int al = e / FI, f = e - al * FI;
        const int atom = a0 + al;
        const int d = deg[atom];
        const int4 nb = *reinterpret_cast<const int4*>(nbr + atom * MAX_D);
        float s = 0.f;
        if (d > 0) s += x[(size_t)nb.x * FI + f];
        if (d > 1) s += x[(size_t)nb.y * FI + f];
        if (d > 2) s += x[(size_t)nb.z * FI + f];
        if (d > 3) s += x[(size_t)nb.w * FI + f];
        nsum[e] = s;
    }
}

// ---------------- Affine: out = selu(x@Ws[d] + nsum@Wn[d] + b[d]) ----------------
// Weights staged in LDS once per block (grid-stride amortizes). x/nsum rows are
// read direct from global: all FO lanes of one atom hit the same address ->
// broadcast, L1-served. Thread = (atom, out-feature).
template<int FI, int FO>
__launch_bounds__(256)
__global__ void affine_kernel(const float* __restrict__ x,
                              const float* __restrict__ nsum,
                              const float* __restrict__ Ws,
                              const float* __restrict__ Wn,
                              const float* __restrict__ bias,
                              const int*   __restrict__ deg,
                              float*       __restrict__ out,
                              int a0, int total /* = cnt*FO */)
{
    __shared__ float ws_lds[NDEG_ * FI * FO];
    __shared__ float wn_lds[NDEG_ * FI * FO];
    __shared__ float b_lds[NDEG_ * FO];
    for (int e = threadIdx.x; e < NDEG_ * FI * FO; e += 256) {
        ws_lds[e] = Ws[e];
        wn_lds[e] = Wn[e];
    }
    for (int e = threadIdx.x; e < NDEG_ * FO; e += 256) b_lds[e] = bias[e];
    __syncthreads();

    for (int e = blockIdx.x * 256 + threadIdx.x; e < total; e += gridDim.x * 256) {
        const int al = e / FO, o = e - al * FO;
        const int atom = a0 + al;
        const int d = deg[atom];
        float acc = b_lds[d * FO + o];
        const float* __restrict__ xr = x + (size_t)atom * FI;
        const float* __restrict__ nr = nsum + (size_t)al * FI;
        const float* __restrict__ wsp = ws_lds + d * FI * FO + o;
        const float* __restrict__ wnp = wn_lds + d * FI * FO + o;
        #pragma unroll 5
        for (int f = 0; f < FI; ++f) {
            acc += xr[f] * wsp[f * FO] + nr[f] * wnp[f * FO];
        }
        out[(size_t)atom * FO + o] = selu_f(acc);
    }
}

template<int FI, int FO>
static void run_conv(const float* x, const float* Ws, const float* Wn, const float* b,
                     const int* nbr, const int* deg, float* out, float* nscr,
                     hipStream_t stream)
{
    const int ch = (NSUM_CAP / FI) < N_ATOMS ? (NSUM_CAP / FI) : N_ATOMS;
    for (int a0 = 0; a0 < N_ATOMS; a0 += ch) {
        const int cnt = (N_ATOMS - a0) < ch ? (N_ATOMS - a0) : ch;
        const int gtot = cnt * FI;
        const int atot = cnt * FO;
        int gblocks = (gtot + 255) / 256; if (gblocks > 8192) gblocks = 8192;
        gather_kernel<FI><<<gblocks, 256, 0, stream>>>(x, nbr, deg, nscr, a0, gtot);
        affine_kernel<FI, FO><<<1024, 256, 0, stream>>>(x, nscr, Ws, Wn, b, deg, out, a0, atot);
    }
}

// ---------------- GraphGather readout + dense->softmax head ----------------
__launch_bounds__(64)
__global__ void readout_kernel(const float* __restrict__ x4,
                               const int*   __restrict__ mem,
                               const float* __restrict__ Wd2,
                               const float* __restrict__ bd2,
                               float*       __restrict__ p)
{
    const int g = blockIdx.x;
    const int t = threadIdx.x;

    int lo = 0, hi = N_ATOMS;                    // lower_bound(g)
    while (lo < hi) { int mid = (lo + hi) >> 1; if (mem[mid] < g) lo = mid + 1; else hi = mid; }
    int lo2 = lo, hi2 = N_ATOMS;                 // lower_bound(g+1)
    while (lo2 < hi2) { int mid = (lo2 + hi2) >> 1; if (mem[mid] < g + 1) lo2 = mid + 1; else hi2 = mid; }

    __shared__ float r[72];
    if (t < 36) {
        float s = 0.f, m = -3.4e38f;
        for (int a = lo; a < lo2; ++a) {
            float v = x4[(size_t)a * 36 + t];
            s += v;
            m = fmaxf(m, v);
        }
        if (lo2 == lo) m = 0.f;                  // empty graph -> 0
        r[t]      = selu_f(s);
        r[36 + t] = selu_f(m);
    }
    __syncthreads();
    if (t < 24) {
        float acc = bd2[t];
        #pragma unroll
        for (int f = 0; f < 72; ++f) acc += r[f] * Wd2[f * 24 + t];
        float part = __shfl_xor(acc, 1);
        p[g * 24 + t] = 1.f / (1.f + __expf(part - acc));
    }
}

// ---------------- Head: y1 = p @ Wl1 + bl1 ----------------
__launch_bounds__(256)
__global__ void dense1_kernel(const float* __restrict__ p,
                              const float* __restrict__ Wl1,
                              const float* __restrict__ bl1,
                              float*       __restrict__ y1)
{
    const int idx = blockIdx.x * 256 + threadIdx.x;
    if (idx >= B_GR * 96) return;
    const int row = idx / 96, c = idx - row * 96;
    float acc = bl1[c];
    const float* pr = p + row * 24;
    #pragma unroll
    for (int f = 0; f < 24; ++f) acc += pr[f] * Wl1[f * 96 + c];
    y1[idx] = acc;
}

// ---------------- Column mean/rstd over batch (deterministic tree) ----------------
template<int C>
__launch_bounds__(256)
__global__ void stats_kernel(const float* __restrict__ y, float* __restrict__ st)
{
    const int c = blockIdx.x;
    float s = 0.f, q = 0.f;
    for (int r = threadIdx.x; r < B_GR; r += 256) {
        const float v = y[r * C + c];
        s += v; q += v * v;
    }
    __shared__ float ss[256], qq[256];
    ss[threadIdx.x] = s; qq[threadIdx.x] = q;
    __syncthreads();
    for (int off = 128; off > 0; off >>= 1) {
        if (threadIdx.x < off) {
            ss[threadIdx.x] += ss[threadIdx.x + off];
            qq[threadIdx.x] += qq[threadIdx.x + off];
        }
        __syncthreads();
    }
    if (threadIdx.x == 0) {
        const float mean = ss[0] / (float)B_GR;
        const float var  = qq[0] / (float)B_GR - mean * mean;
        st[c]     = mean;
        st[C + c] = rsqrtf(var + 1e-5f);
    }
}

// ---------------- h1 = relu(bn(y1)); y2 = h1 @ Wl2 + bl2 ----------------
__launch_bounds__(256)
__global__ void dense2_kernel(const float* __restrict__ y1,
                              const float* __restrict__ st1,
                              const float* __restrict__ g1,
                              const float* __restrict__ be1,
                              const float* __restrict__ Wl2,
                              const float* __restrict__ bl2,
                              float*       __restrict__ y2)
{
    __shared__ float h[4 * 96];
    const int r0 = blockIdx.x * 4;
    for (int e = threadIdx.x; e < 4 * 96; e += 256) {
        const int rr = e / 96, c = e - rr * 96;
        float v = y1[(r0 + rr) * 96 + c];
        v = (v - st1[c]) * st1[96 + c] * g1[c] + be1[c];
        h[e] = fmaxf(v, 0.f);
    }
    __syncthreads();
    for (int e = threadIdx.x; e < 4 * 63; e += 256) {
        const int rr = e / 63, o = e - rr * 63;
        float acc = bl2[o];
        #pragma unroll
        for (int f = 0; f < 96; ++f) acc += h[rr * 96 + f] * Wl2[f * 63 + o];
        y2[(r0 + rr) * 63 + o] = acc;
    }
}

// ---------------- h2 = relu(bn(y2)); out = sigmoid(h2 @ Wl3 + bl3) ----------------
__launch_bounds__(320)
__global__ void dense3_kernel(const float* __restrict__ y2,
                              const float* __restrict__ st2,
                              const float* __restrict__ g2,
                              const float* __restrict__ be2,
                              const float* __restrict__ Wl3,
                              const float* __restrict__ bl3,
                              float*       __restrict__ out)
{
    __shared__ float h[2 * 63];
    const int r0 = blockIdx.x * 2;
    for (int e = threadIdx.x; e < 2 * 63; e += 320) {
        const int rr = e / 63, c = e - rr * 63;
        float v = y2[(r0 + rr) * 63 + c];
        v = (v - st2[c]) * st2[63 + c] * g2[c] + be2[c];
        h[e] = fmaxf(v, 0.f);
    }
    __syncthreads();
    for (int e = threadIdx.x; e < 2 * 138; e += 320) {
        const int rr = e / 138, o = e - rr * 138;
        float acc = bl3[o];
        #pragma unroll
        for (int f = 0; f < 63; ++f) acc += h[rr * 63 + f] * Wl3[f * 138 + o];
        out[(r0 + rr) * 138 + o] = 1.f / (1.f + __expf(-acc));
    }
}

extern "C" void kernel_launch(void* const* d_in, const int* in_sizes, int n_in,
                              void* d_out, int out_size, void* d_ws, size_t ws_size,
                              hipStream_t stream)
{
    (void)in_sizes; (void)n_in; (void)out_size; (void)ws_size;

    const float* af  = (const float*)d_in[0];
    const float* Ws1 = (const float*)d_in[1];
    const float* Wn1 = (const float*)d_in[2];
    const float* b1  = (const float*)d_in[3];
    const float* Ws2 = (const float*)d_in[4];
    const float* Wn2 = (const float*)d_in[5];
    const float* b2  = (const float*)d_in[6];
    const float* Ws3 = (const float*)d_in[7];
    const float* Wn3 = (const float*)d_in[8];
    const float* b3  = (const float*)d_in[9];
    const float* Ws4 = (const float*)d_in[10];
    const float* Wn4 = (const float*)d_in[11];
    const float* b4  = (const float*)d_in[12];
    const float* Wd2 = (const float*)d_in[13];
    const float* bd2 = (const float*)d_in[14];
    const float* Wl1 = (const float*)d_in[15];
    const float* bl1 = (const float*)d_in[16];
    const float* g1  = (const float*)d_in[17];
    const float* be1 = (const float*)d_in[18];
    const float* Wl2 = (const float*)d_in[19];
    const float* bl2 = (const float*)d_in[20];
    const float* g2  = (const float*)d_in[21];
    const float* be2 = (const float*)d_in[22];
    const float* Wl3 = (const float*)d_in[23];
    const float* bl3 = (const float*)d_in[24];
    const int*   nbr = (const int*)d_in[25];
    const int*   deg = (const int*)d_in[26];
    const int*   mem = (const int*)d_in[27];

    float* ws = (float*)d_ws;
    // Regions: bufA (N*27 floats): x1, x3, then head scratch.
    //          bufB (N*36 floats): x2, x4.
    //          nscr (NSUM_CAP floats): per-layer chunked neighbor sums.
    float* bufA = ws;
    float* bufB = ws + (size_t)N_ATOMS * 27;
    float* nscr = bufB + (size_t)N_ATOMS * 36;
    float* x1 = bufA;
    float* x2 = bufB;
    float* x3 = bufA;
    float* x4 = bufB;
    float* p   = bufA;                       // B*24  (x3 dead after conv4)
    float* y1  = bufA + 393216;              // B*96
    float* y2  = bufA + 393216 + 1572864;    // B*63
    float* st1 = bufA + 393216 + 1572864 + 1032192;        // 192
    float* st2 = st1 + 192;                                 // 126

    run_conv<75, 15>(af, Ws1, Wn1, b1, nbr, deg, x1, nscr, stream);
    run_conv<15, 20>(x1, Ws2, Wn2, b2, nbr, deg, x2, nscr, stream);
    run_conv<20, 27>(x2, Ws3, Wn3, b3, nbr, deg, x3, nscr, stream);
    run_conv<27, 36>(x3, Ws4, Wn4, b4, nbr, deg, x4, nscr, stream);

    readout_kernel<<<B_GR, 64, 0, stream>>>(x4, mem, Wd2, bd2, p);

    dense1_kernel<<<(B_GR * 96) / 256, 256, 0, stream>>>(p, Wl1, bl1, y1);
    stats_kernel<96><<<96, 256, 0, stream>>>(y1, st1);
    dense2_kernel<<<B_GR / 4, 256, 0, stream>>>(y1, st1, g1, be1, Wl2, bl2, y2);
    stats_kernel<63><<<63, 256, 0, stream>>>(y2, st2);
    dense3_kernel<<<B_GR / 2, 320, 0, stream>>>(y2, st2, g2, be2, Wl3, bl3, (float*)d_out);
}